// Round 16
// baseline (310.155 us; speedup 1.0000x reference)
//
#include <hip/hip_runtime.h>
#include <hip/hip_bf16.h>
#include <cstdint>

#define N_NODES 100000
#define N_EDGES 1600000
#define NBUK 391   // ceil(N_NODES / 256) buckets of 256 dst nodes
#define CHUNK 8192
#define NBLK 391   // ceil(2*N_EDGES / CHUNK)
#define MAXB 10240 // LDS staging capacity per bucket (mean 8192, +22σ)
#define NSB 16     // src super-buckets: src>>13 in [0,13)

static inline size_t alup(size_t x) { return (x + 255) & ~(size_t)255; }

typedef __attribute__((ext_vector_type(8))) short bf16x8;
typedef __attribute__((ext_vector_type(4))) float f32x4;
typedef __attribute__((ext_vector_type(2))) float f32x2;
union U4 { uint4 u; bf16x8 v; };

static __device__ __forceinline__ uint32_t pack_bf16x2(float a, float b) {
  uint32_t ua = __float_as_uint(a); ua += 0x7FFF + ((ua >> 16) & 1);
  uint32_t ub = __float_as_uint(b); ub += 0x7FFF + ((ub >> 16) & 1);
  return (ua >> 16) | (ub & 0xFFFF0000u);
}
static __device__ __forceinline__ float bf16lo(uint32_t u) { return __uint_as_float(u << 16); }
static __device__ __forceinline__ float bf16hi(uint32_t u) { return __uint_as_float(u & 0xFFFF0000u); }

// fp8 e4m3 decode-accumulate into packed f32x2 accumulators (v_pk_add_f32):
// 4 cvt + 4 pk_add per uint2 (was 4 cvt + 8 scalar adds).
#define ACC8V(u)                                                   \
  {                                                                \
    a01 += __builtin_amdgcn_cvt_pk_f32_fp8((u).x, false);          \
    a23 += __builtin_amdgcn_cvt_pk_f32_fp8((u).x, true);           \
    a45 += __builtin_amdgcn_cvt_pk_f32_fp8((u).y, false);          \
    a67 += __builtin_amdgcn_cvt_pk_f32_fp8((u).y, true);           \
  }

// ---------------- prep kernels (atomic-free CSR build) ----------------

// Per-block histogram -> row of cntmat (coalesced stores, NO global atomics).
__global__ __launch_bounds__(512) void k_hist(const int* __restrict__ ei,
                                              int* __restrict__ cntmat) {
  __shared__ int hist[NBUK];
  const int tid = threadIdx.x;
  const int base = blockIdx.x * CHUNK;
  const int n = min(CHUNK, 2 * N_EDGES - base);
  for (int i = tid; i < NBUK; i += 512) hist[i] = 0;
  __syncthreads();
  for (int i = tid; i < n; i += 512) {
    const int e = base + i;
    const int dst = (e < N_EDGES) ? ei[N_EDGES + e] : ei[e - N_EDGES];
    atomicAdd(&hist[dst >> 8], 1);
  }
  __syncthreads();
  for (int i = tid; i < NBUK; i += 512)
    cntmat[(size_t)blockIdx.x * NBUK + i] = hist[i];
}

// Column scan: one wave per bucket; cntmat[blk][b] -> exclusive prefix over blk
// (in place); bucket total -> bukcnt[b].
__global__ __launch_bounds__(64) void k_scanB(int* __restrict__ cntmat,
                                              int* __restrict__ bukcnt) {
  const int b = blockIdx.x;
  const int lane = threadIdx.x;
  const int PER = (NBLK + 63) / 64;  // 7
  int v[PER]; int s = 0;
#pragma unroll
  for (int j = 0; j < PER; ++j) {
    const int blk = lane * PER + j;
    v[j] = (blk < NBLK) ? cntmat[(size_t)blk * NBUK + b] : 0;
    s += v[j];
  }
  int incl = s;
#pragma unroll
  for (int off = 1; off < 64; off <<= 1) {
    const int u = __shfl_up(incl, off);
    if (lane >= off) incl += u;
  }
  int run = incl - s;
#pragma unroll
  for (int j = 0; j < PER; ++j) {
    const int blk = lane * PER + j;
    if (blk < NBLK) cntmat[(size_t)blk * NBUK + b] = run;
    run += v[j];
  }
  if (lane == 63) bukcnt[b] = incl;
}

// Scan 391 bucket totals -> exclusive bbase[0..NBUK]; also seeds rowptr[N_NODES].
__global__ __launch_bounds__(512) void k_scan2(const int* __restrict__ bsum,
                                               int* __restrict__ bbase,
                                               int* __restrict__ rowptr) {
  const int tid = threadIdx.x;
  const int v = (tid < NBUK) ? bsum[tid] : 0;
  int incl = v;
#pragma unroll
  for (int off = 1; off < 64; off <<= 1) {
    const int u = __shfl_up(incl, off);
    if ((tid & 63) >= off) incl += u;
  }
  __shared__ int wsum[8];
  if ((tid & 63) == 63) wsum[tid >> 6] = incl;
  __syncthreads();
  const int wid = tid >> 6;
  int add = 0;
#pragma unroll
  for (int k = 0; k < 7; ++k)
    if (k < wid) add += wsum[k];
  incl += add;
  if (tid < NBUK) bbase[tid] = incl - v;
  if (tid == NBUK - 1) bbase[NBUK] = incl;  // = 2*N_EDGES
  if (tid == 0) rowptr[N_NODES] = 2 * N_EDGES;
}

// Pass 1: multisplit into 391 dst-buckets, coalesced writes; bucket id cached in LDS.
// Global write bases precomputed (bbase + per-block prefix) -> NO global atomics.
// CHUNK=8192: avg bucket burst ~21 words (~84B) -> less partial-line write waste.
__global__ __launch_bounds__(512) void k_bin(const int* __restrict__ ei,
                                             const int* __restrict__ bbase,
                                             const int* __restrict__ cntpre,
                                             uint32_t* __restrict__ ebuf) {
  __shared__ int hist[NBUK];
  __shared__ int excl[NBUK + 1];
  __shared__ int gbase[NBUK];
  __shared__ uint32_t stage[CHUNK];          // 32 KB
  __shared__ unsigned short sbuk[CHUNK];     // 16 KB
  const int tid = threadIdx.x;
  const int base = blockIdx.x * CHUNK;
  const int n = min(CHUNK, 2 * N_EDGES - base);
  for (int i = tid; i < NBUK; i += 512) {
    hist[i] = 0;
    gbase[i] = bbase[i] + cntpre[(size_t)blockIdx.x * NBUK + i];
  }
  __syncthreads();
  uint32_t pk[16]; int bk[16]; int rk[16];
#pragma unroll
  for (int i = 0; i < 16; ++i) {
    const int li = i * 512 + tid;
    bk[i] = -1;
    if (li < n) {
      const int e = base + li;
      const int src = ei[e];
      const int dst = (e < N_EDGES) ? ei[N_EDGES + e] : ei[e - N_EDGES];
      bk[i] = dst >> 8;
      pk[i] = ((uint32_t)(dst & 255) << 17) | (uint32_t)src;
      rk[i] = atomicAdd(&hist[bk[i]], 1);
    }
  }
  __syncthreads();
  if (tid < 64) {  // block-local exclusive prefix of hist (LDS only)
    int c[7]; int s = 0;
#pragma unroll
    for (int j = 0; j < 7; ++j) {
      const int b = tid * 7 + j;
      c[j] = (b < NBUK) ? hist[b] : 0;
      s += c[j];
    }
    int incl = s;
#pragma unroll
    for (int off = 1; off < 64; off <<= 1) {
      const int v = __shfl_up(incl, off);
      if (tid >= off) incl += v;
    }
    int run = incl - s;
#pragma unroll
    for (int j = 0; j < 7; ++j) {
      const int b = tid * 7 + j;
      if (b < NBUK) {
        excl[b] = run;
        run += c[j];
      }
    }
    if (tid == 63) excl[NBUK] = incl;
  }
  __syncthreads();
#pragma unroll
  for (int i = 0; i < 16; ++i)
    if (bk[i] >= 0) {
      const int pos = excl[bk[i]] + rk[i];
      stage[pos] = pk[i];
      sbuk[pos] = (unsigned short)bk[i];
    }
  __syncthreads();
  for (int i = tid; i < n; i += 512) {
    const int b = sbuk[i];
    ebuf[gbase[b] + (i - excl[b])] = stage[i];
  }
}

// Pass 2: per-bucket counting sort by (dst_local, src>>13); emits rowptr + dinv.
__global__ __launch_bounds__(512) void k_csr(const uint32_t* __restrict__ ebuf,
                                             const int* __restrict__ bbase,
                                             int* __restrict__ col,
                                             int* __restrict__ rowptr,
                                             float* __restrict__ dinv) {
  __shared__ int cnt[256 * NSB];   // 16 KB
  __shared__ int lstage[MAXB];     // 40 KB
  __shared__ int wsum[4];
  const int b = blockIdx.x;
  const int node0 = b << 8;
  const int gstart = bbase[b];
  const int total = bbase[b + 1] - gstart;
  const int tid = threadIdx.x;
  for (int i = tid; i < 256 * NSB; i += 512) cnt[i] = 0;
  __syncthreads();
  for (int i = tid; i < total; i += 512) {
    const uint32_t pk = ebuf[gstart + i];
    atomicAdd(&cnt[(pk >> 17) * NSB + ((pk & 0x1FFFF) >> 13)], 1);
  }
  __syncthreads();
  int nodetotal = 0;
  if (tid < 256) {
#pragma unroll
    for (int s = 0; s < NSB; ++s) nodetotal += cnt[tid * NSB + s];
    int incl = nodetotal;
#pragma unroll
    for (int off = 1; off < 64; off <<= 1) {
      const int u = __shfl_up(incl, off);
      if ((tid & 63) >= off) incl += u;
    }
    if ((tid & 63) == 63) wsum[tid >> 6] = incl;
    nodetotal = incl;   // stash inclusive value
  }
  __syncthreads();
  if (tid < 256) {
    int deg = 0;
#pragma unroll
    for (int s = 0; s < NSB; ++s) deg += cnt[tid * NSB + s];
    const int wid = tid >> 6;
    int add = 0;
#pragma unroll
    for (int k = 0; k < 3; ++k)
      if (k < wid) add += wsum[k];
    const int prefix = nodetotal + add - deg;
    const int node = node0 + tid;
    if (node < N_NODES) {
      rowptr[node] = gstart + prefix;
      dinv[node] = rsqrtf((float)(deg + 1));  // +1 self loop
    }
    int run = prefix;
#pragma unroll
    for (int s = 0; s < NSB; ++s) {
      const int c = cnt[tid * NSB + s];
      cnt[tid * NSB + s] = run;
      run += c;
    }
  }
  __syncthreads();
  for (int i = tid; i < total; i += 512) {
    const uint32_t pk = ebuf[gstart + i];
    const int src = pk & 0x1FFFF;
    const int p = atomicAdd(&cnt[(pk >> 17) * NSB + (src >> 13)], 1);
    if (p < MAXB) lstage[p] = src;
    else col[gstart + p] = src;  // overflow fallback (statistically never)
  }
  __syncthreads();
  const int m = min(total, MAXB);
  for (int i = tid; i < m; i += 512) col[gstart + i] = lstage[i];
}

// ---------------- MFMA GEMM: hs = dinv[row] * (x @ W.T) ----------------
// FP8OUT: pack to fp8 e4m3 (row = OUT/4 u32); else bf16x2 (row = OUT/2 u32).
template<int OUT, bool FP32IN, bool FP8OUT>
__global__ __launch_bounds__(256) void k_gemm(const void* __restrict__ xin,
                                              const float* __restrict__ W,
                                              const float* __restrict__ dinv,
                                              uint32_t* __restrict__ hout) {
  constexpr int NT = OUT / 16;
  __shared__ uint32_t wlds[OUT * 68];     // W bf16x2, row n stride 68 u32 (pad)
  __shared__ float clds[4][16][36];       // per-wave C staging (2 n-tiles)
  const int tid = threadIdx.x;
  const int lane = tid & 63;
  const int wv = tid >> 6;
  for (int idx = tid; idx < OUT * 32; idx += 256) {
    const int n = idx >> 5;
    const int kq = idx & 31;              // 4 k per step
    const float4 w4 = *(const float4*)(W + (size_t)n * 128 + kq * 4);
    wlds[n * 68 + kq * 2 + 0] = pack_bf16x2(w4.x, w4.y);
    wlds[n * 68 + kq * 2 + 1] = pack_bf16x2(w4.z, w4.w);
  }
  __syncthreads();
  const int row0 = blockIdx.x * 64 + wv * 16;
  const int r = min(row0 + (lane & 15), N_NODES - 1);
  const int kh = lane >> 4;               // k-octet selector 0..3
  U4 a[4];
  if (FP32IN) {
    const float* xp = (const float*)xin + (size_t)r * 128 + kh * 8;
#pragma unroll
    for (int kb = 0; kb < 4; ++kb) {
      const float4 lo = *(const float4*)(xp + kb * 32);
      const float4 hi = *(const float4*)(xp + kb * 32 + 4);
      a[kb].u = make_uint4(pack_bf16x2(lo.x, lo.y), pack_bf16x2(lo.z, lo.w),
                           pack_bf16x2(hi.x, hi.y), pack_bf16x2(hi.z, hi.w));
    }
  } else {
    const uint4* xp = (const uint4*)xin + (size_t)r * 16 + kh;
#pragma unroll
    for (int kb = 0; kb < 4; ++kb) a[kb].u = xp[kb * 4];
  }
#pragma unroll
  for (int np = 0; np < NT; np += 2) {
#pragma unroll
    for (int t = 0; t < 2; ++t) {
      f32x4 acc = {0.f, 0.f, 0.f, 0.f};
      const int n = (np + t) * 16 + (lane & 15);
#pragma unroll
      for (int kb = 0; kb < 4; ++kb) {
        U4 bf;
        bf.u = *(const uint4*)(wlds + n * 68 + kb * 16 + kh * 4);
        acc = __builtin_amdgcn_mfma_f32_16x16x32_bf16(a[kb].v, bf.v, acc, 0, 0, 0);
      }
#pragma unroll
      for (int rr = 0; rr < 4; ++rr)
        clds[wv][kh * 4 + rr][t * 16 + (lane & 15)] = acc[rr];
    }
    __syncthreads();
    const int orow = lane & 15;
    const int colg = (lane >> 4) * 8;     // 0,8,16,24
    const int grow = row0 + orow;
    const float di = dinv[grow < N_NODES ? grow : 0];
    const float4 c0 = *(const float4*)&clds[wv][orow][colg];
    const float4 c1 = *(const float4*)&clds[wv][orow][colg + 4];
    if (grow < N_NODES) {
      if (FP8OUT) {
        uint32_t u0 = __builtin_amdgcn_cvt_pk_fp8_f32(di * c0.x, di * c0.y, 0, false);
        u0 = __builtin_amdgcn_cvt_pk_fp8_f32(di * c0.z, di * c0.w, u0, true);
        uint32_t u1 = __builtin_amdgcn_cvt_pk_fp8_f32(di * c1.x, di * c1.y, 0, false);
        u1 = __builtin_amdgcn_cvt_pk_fp8_f32(di * c1.z, di * c1.w, u1, true);
        *(uint2*)(hout + (size_t)grow * (OUT / 4) + np * 4 + colg / 4) = make_uint2(u0, u1);
      } else {
        const uint4 pkv = make_uint4(pack_bf16x2(di * c0.x, di * c0.y),
                                     pack_bf16x2(di * c0.z, di * c0.w),
                                     pack_bf16x2(di * c1.x, di * c1.y),
                                     pack_bf16x2(di * c1.z, di * c1.w));
        *(uint4*)(hout + (size_t)grow * (OUT / 2) + np * 8 + colg / 2) = pkv;
      }
    }
    __syncthreads();
  }
}

// ---------------- aggregation (fp8 gather): out[i] = di*(sum_c hs[c] + hs[i]) + b ----------------
// Quad-edge layout: lane quarter q handles edges 4j+q; 16 lanes x uint2 = full 128B row;
// packed f32x2 accumulators (v_pk_add_f32); quarters combined via shfl_xor(32),(16);
// bf16x2 output.
template<bool RELU>
__global__ __launch_bounds__(256) void k_agg128(const uint2* __restrict__ h8,
                                                const float* __restrict__ dinv,
                                                const int* __restrict__ rowptr,
                                                const int* __restrict__ col,
                                                const float* __restrict__ bias,
                                                uint32_t* __restrict__ out) {
  const int lane = threadIdx.x & 63;
  const int q = lane >> 4;      // edge sub-slot 0..3
  const int t = lane & 15;      // uint2 index: cols {8t..8t+7}
  const int bswz = (blockIdx.x & 7) * (gridDim.x >> 3) + (blockIdx.x >> 3);
  const int node = bswz * 4 + (threadIdx.x >> 6);
  if (node >= N_NODES) return;
  const int e0 = rowptr[node], e1 = rowptr[node + 1];
  f32x2 a01 = {0.f, 0.f}, a23 = {0.f, 0.f}, a45 = {0.f, 0.f}, a67 = {0.f, 0.f};
  if (q == 0) {  // self-loop counted once
    const uint2 us = h8[(size_t)node * 16 + t];
    ACC8V(us);
  }
  for (int eb = e0; eb < e1; eb += 64) {
    const int n = min(64, e1 - eb);
    const int ce = col[min(eb + lane, e1 - 1)];
    const int qn = (n + 3) >> 2;
#pragma unroll 4
    for (int j = 0; j < qn; ++j) {
      const int idx = 4 * j + q;
      const int c = __shfl(ce, idx);
      if (idx < n) {
        const uint2 u = h8[(size_t)c * 16 + t];
        ACC8V(u);
      }
    }
  }
  float a0 = a01.x, a1 = a01.y, a2 = a23.x, a3 = a23.y;
  float a4 = a45.x, a5 = a45.y, a6 = a67.x, a7 = a67.y;
  a0 += __shfl_xor(a0, 32); a1 += __shfl_xor(a1, 32);
  a2 += __shfl_xor(a2, 32); a3 += __shfl_xor(a3, 32);
  a4 += __shfl_xor(a4, 32); a5 += __shfl_xor(a5, 32);
  a6 += __shfl_xor(a6, 32); a7 += __shfl_xor(a7, 32);
  a0 += __shfl_xor(a0, 16); a1 += __shfl_xor(a1, 16);
  a2 += __shfl_xor(a2, 16); a3 += __shfl_xor(a3, 16);
  a4 += __shfl_xor(a4, 16); a5 += __shfl_xor(a5, 16);
  a6 += __shfl_xor(a6, 16); a7 += __shfl_xor(a7, 16);
  if (q == 0) {
    const float di = dinv[node];
    const float4 b0 = ((const float4*)bias)[t * 2];
    const float4 b1 = ((const float4*)bias)[t * 2 + 1];
    float o0 = di * a0 + b0.x, o1 = di * a1 + b0.y;
    float o2 = di * a2 + b0.z, o3 = di * a3 + b0.w;
    float o4 = di * a4 + b1.x, o5 = di * a5 + b1.y;
    float o6 = di * a6 + b1.z, o7 = di * a7 + b1.w;
    if (RELU) {
      o0 = fmaxf(o0, 0.f); o1 = fmaxf(o1, 0.f); o2 = fmaxf(o2, 0.f); o3 = fmaxf(o3, 0.f);
      o4 = fmaxf(o4, 0.f); o5 = fmaxf(o5, 0.f); o6 = fmaxf(o6, 0.f); o7 = fmaxf(o7, 0.f);
    }
    ((uint4*)out)[(size_t)node * 16 + t] =
        make_uint4(pack_bf16x2(o0, o1), pack_bf16x2(o2, o3),
                   pack_bf16x2(o4, o5), pack_bf16x2(o6, o7));
  }
}

// Final layer, fp8 gather (row = 8 uint2 = 64 B): octet-edge layout; packed f32x2
// accumulators; combine via shfl_xor(32,16,8); fused bias + log_softmax over
// 8 lanes x 8 cols (shfl_xor 4,2,1); fp32 out.
__global__ __launch_bounds__(256) void k_agg64_lsm(const uint2* __restrict__ h8,
                                                   const float* __restrict__ dinv,
                                                   const int* __restrict__ rowptr,
                                                   const int* __restrict__ col,
                                                   const float* __restrict__ bias,
                                                   float* __restrict__ out) {
  const int lane = threadIdx.x & 63;
  const int q = lane >> 3;      // edge sub-slot 0..7
  const int t = lane & 7;       // uint2 index: cols {8t..8t+7}
  const int bswz = (blockIdx.x & 7) * (gridDim.x >> 3) + (blockIdx.x >> 3);
  const int node = bswz * 4 + (threadIdx.x >> 6);
  if (node >= N_NODES) return;
  const int e0 = rowptr[node], e1 = rowptr[node + 1];
  f32x2 a01 = {0.f, 0.f}, a23 = {0.f, 0.f}, a45 = {0.f, 0.f}, a67 = {0.f, 0.f};
  if (q == 0) {  // self-loop counted once
    const uint2 us = h8[(size_t)node * 8 + t];
    ACC8V(us);
  }
  for (int eb = e0; eb < e1; eb += 64) {
    const int n = min(64, e1 - eb);
    const int ce = col[min(eb + lane, e1 - 1)];
    const int qn = (n + 7) >> 3;
#pragma unroll 4
    for (int j = 0; j < qn; ++j) {
      const int idx = 8 * j + q;
      const int c = __shfl(ce, idx);
      if (idx < n) {
        const uint2 u = h8[(size_t)c * 8 + t];
        ACC8V(u);
      }
    }
  }
  float a0 = a01.x, a1 = a01.y, a2 = a23.x, a3 = a23.y;
  float a4 = a45.x, a5 = a45.y, a6 = a67.x, a7 = a67.y;
  // reduce over edge octets (bits 3..5 of lane)
  a0 += __shfl_xor(a0, 32); a1 += __shfl_xor(a1, 32);
  a2 += __shfl_xor(a2, 32); a3 += __shfl_xor(a3, 32);
  a4 += __shfl_xor(a4, 32); a5 += __shfl_xor(a5, 32);
  a6 += __shfl_xor(a6, 32); a7 += __shfl_xor(a7, 32);
  a0 += __shfl_xor(a0, 16); a1 += __shfl_xor(a1, 16);
  a2 += __shfl_xor(a2, 16); a3 += __shfl_xor(a3, 16);
  a4 += __shfl_xor(a4, 16); a5 += __shfl_xor(a5, 16);
  a6 += __shfl_xor(a6, 16); a7 += __shfl_xor(a7, 16);
  a0 += __shfl_xor(a0, 8);  a1 += __shfl_xor(a1, 8);
  a2 += __shfl_xor(a2, 8);  a3 += __shfl_xor(a3, 8);
  a4 += __shfl_xor(a4, 8);  a5 += __shfl_xor(a5, 8);
  a6 += __shfl_xor(a6, 8);  a7 += __shfl_xor(a7, 8);
  const float di = dinv[node];
  const float4 b0 = ((const float4*)bias)[t * 2];
  const float4 b1 = ((const float4*)bias)[t * 2 + 1];
  const float v0 = di * a0 + b0.x, v1 = di * a1 + b0.y;
  const float v2 = di * a2 + b0.z, v3 = di * a3 + b0.w;
  const float v4 = di * a4 + b1.x, v5 = di * a5 + b1.y;
  const float v6 = di * a6 + b1.z, v7 = di * a7 + b1.w;
  float m = fmaxf(fmaxf(fmaxf(v0, v1), fmaxf(v2, v3)),
                  fmaxf(fmaxf(v4, v5), fmaxf(v6, v7)));
#pragma unroll
  for (int off = 4; off > 0; off >>= 1) m = fmaxf(m, __shfl_xor(m, off));
  float s = __expf(v0 - m) + __expf(v1 - m) + __expf(v2 - m) + __expf(v3 - m) +
            __expf(v4 - m) + __expf(v5 - m) + __expf(v6 - m) + __expf(v7 - m);
#pragma unroll
  for (int off = 4; off > 0; off >>= 1) s += __shfl_xor(s, off);
  const float ls = m + __logf(s);
  if (q == 0) {
    float* op = out + (size_t)node * 64 + t * 8;
    *(float4*)op = make_float4(v0 - ls, v1 - ls, v2 - ls, v3 - ls);
    *(float4*)(op + 4) = make_float4(v4 - ls, v5 - ls, v6 - ls, v7 - ls);
  }
}

// ---------------- launch ----------------

extern "C" void kernel_launch(void* const* d_in, const int* in_sizes, int n_in,
                              void* d_out, int out_size, void* d_ws, size_t ws_size,
                              hipStream_t stream) {
  const float* x  = (const float*)d_in[0];
  const int*   ei = (const int*)d_in[1];
  const float* W0 = (const float*)d_in[2];
  const float* b0 = (const float*)d_in[3];
  const float* W1 = (const float*)d_in[4];
  const float* b1 = (const float*)d_in[5];
  const float* W2 = (const float*)d_in[6];
  const float* b2 = (const float*)d_in[7];
  float* outp = (float*)d_out;

  char* p = (char*)d_ws;
  float* dinv    = (float*)p; p += alup((size_t)N_NODES * 4);
  int*   rowptr  = (int*)p;   p += alup((size_t)(N_NODES + 1) * 4);
  int*   bukcnt  = (int*)p;   p += alup((size_t)NBUK * 4);
  int*   bbase   = (int*)p;   p += alup((size_t)(NBUK + 1) * 4);
  int*   cntmat  = (int*)p;   p += alup((size_t)NBLK * NBUK * 4);
  int*   col     = (int*)p;   p += alup((size_t)2 * N_EDGES * 4);
  float* bufA    = (float*)p; p += alup((size_t)N_NODES * 128 * 4);
  float* bufB    = (float*)p;
  uint32_t* ebuf = (uint32_t*)bufA;       // pass-1 staging aliases bufA
  uint32_t* h16  = (uint32_t*)bufA;       // gemm output buffer (fp8)
  uint32_t* a16  = (uint32_t*)bufB;       // bf16x2 agg output (layers 0/1)

  k_hist<<<NBLK, 512, 0, stream>>>(ei, cntmat);
  k_scanB<<<NBUK, 64, 0, stream>>>(cntmat, bukcnt);
  k_scan2<<<1, 512, 0, stream>>>(bukcnt, bbase, rowptr);
  k_bin<<<NBLK, 512, 0, stream>>>(ei, bbase, cntmat, ebuf);
  k_csr<<<NBUK, 512, 0, stream>>>(ebuf, bbase, col, rowptr, dinv);

  const int gblk = (N_NODES + 63) / 64;   // 1563
  k_gemm<128, true, true><<<gblk, 256, 0, stream>>>(x, W0, dinv, h16);
  k_agg128<true><<<N_NODES / 4, 256, 0, stream>>>((const uint2*)h16, dinv, rowptr, col, b0, a16);
  k_gemm<128, false, true><<<gblk, 256, 0, stream>>>(a16, W1, dinv, h16);
  k_agg128<true><<<N_NODES / 4, 256, 0, stream>>>((const uint2*)h16, dinv, rowptr, col, b1, a16);
  k_gemm<64, false, true><<<gblk, 256, 0, stream>>>(a16, W2, dinv, h16);
  k_agg64_lsm<<<N_NODES / 4, 256, 0, stream>>>((const uint2*)h16, dinv, rowptr, col, b2, outp);
}